// Round 11
// baseline (3357.272 us; speedup 1.0000x reference)
//
#include <hip/hip_runtime.h>
#include <math.h>

#define DEVI static __device__ __forceinline__

typedef __attribute__((ext_vector_type(8))) short bf16x8;
typedef __attribute__((ext_vector_type(4))) short bf16x4;
typedef __attribute__((ext_vector_type(8))) unsigned short ushort8;
typedef __attribute__((ext_vector_type(4))) unsigned short us4;
typedef __attribute__((ext_vector_type(4))) float f32x4;

DEVI unsigned short f32_bf16(float f) {
  unsigned int u = __float_as_uint(f);
  u += 0x7fffu + ((u >> 16) & 1u);
  return (unsigned short)(u >> 16);
}
DEVI float bf16_f32(unsigned short h) {
  return __uint_as_float(((unsigned int)h) << 16);
}

DEVI void async16(void* lds, const void* g) {
  __builtin_amdgcn_global_load_lds(
      (const __attribute__((address_space(1))) void*)g,
      (__attribute__((address_space(3))) void*)lds,
      16, 0, 0);
}

#if __has_builtin(__builtin_amdgcn_mfma_f32_16x16x16bf16_1k)
DEVI f32x4 mfma16(bf16x4 a, bf16x4 b, f32x4 c) {
  return __builtin_amdgcn_mfma_f32_16x16x16bf16_1k(a, b, c, 0, 0, 0);
}
#else
DEVI f32x4 mfma16(bf16x4 a, bf16x4 b, f32x4 c) {
  asm volatile("v_mfma_f32_16x16x16_bf16 %0, %1, %2, %0" : "+v"(c) : "v"(a), "v"(b));
  return c;
}
#endif

// ---------------------------------------------------------------- casts ----
__global__ __launch_bounds__(256) void cast_bf16_kernel(
    const float* __restrict__ src, unsigned short* __restrict__ dst, long n8) {
  long i = (long)blockIdx.x * 256 + threadIdx.x;
  if (i >= n8) return;
  const float4 a = *(const float4*)(src + i * 8);
  const float4 b = *(const float4*)(src + i * 8 + 4);
  ushort8 o;
  o[0] = f32_bf16(a.x); o[1] = f32_bf16(a.y); o[2] = f32_bf16(a.z); o[3] = f32_bf16(a.w);
  o[4] = f32_bf16(b.x); o[5] = f32_bf16(b.y); o[6] = f32_bf16(b.z); o[7] = f32_bf16(b.w);
  *(ushort8*)(dst + i * 8) = o;
}

// gate/up interleave: dst row 2j = gate j, row 2j+1 = up j.  [16384][2048]
__global__ __launch_bounds__(256) void cast_gu_kernel(
    const float* __restrict__ gate, const float* __restrict__ up,
    unsigned short* __restrict__ dst) {
  long i = (long)blockIdx.x * 256 + threadIdx.x;
  long row = i >> 8;
  long col = (i & 255) * 8;
  const float* src = ((row & 1) ? up : gate) + ((row >> 1) << 11) + col;
  const float4 a = *(const float4*)(src);
  const float4 b = *(const float4*)(src + 4);
  ushort8 o;
  o[0] = f32_bf16(a.x); o[1] = f32_bf16(a.y); o[2] = f32_bf16(a.z); o[3] = f32_bf16(a.w);
  o[4] = f32_bf16(b.x); o[5] = f32_bf16(b.y); o[6] = f32_bf16(b.z); o[7] = f32_bf16(b.w);
  *(ushort8*)(dst + i * 8) = o;
}

// ----------------------------------------------------------------- rope ----
__global__ __launch_bounds__(256) void rope_table_kernel(float2* __restrict__ tab) {
  int idx = blockIdx.x * 256 + threadIdx.x;
  int t = idx >> 6, i = idx & 63;
  float inv = __expf(-(float)(2 * i) * (1.0f / 128.0f) * 13.122363377404328f);
  float f = (float)t * inv;
  tab[idx] = make_float2(cosf(f), sinf(f));
}

__global__ __launch_bounds__(256) void rope_apply_kernel(
    unsigned short* __restrict__ qkv, const float2* __restrict__ tab) {
  const int row = blockIdx.x;
  const int tid = threadIdx.x;
#pragma unroll
  for (int it = 0; it < 5; ++it) {
    int p = tid + it * 256;
    int head = p >> 6, i = p & 63;
    int col = (p < 1024) ? (head * 128 + 2 * i) : (2048 + (head - 16) * 128 + 2 * i);
    unsigned short* ptr = qkv + (long)row * 3072 + col;
    float a = bf16_f32(ptr[0]), b = bf16_f32(ptr[1]);
    float2 cs = tab[row * 64 + i];
    float a2 = a * cs.x - b * cs.y;
    float b2 = a * cs.y + b * cs.x;
    ptr[0] = f32_bf16(a2);
    ptr[1] = f32_bf16(b2);
  }
}

// -------------------------------------------------------------- rmsnorm ----
__global__ __launch_bounds__(256) void rmsnorm_kernel(
    const float* __restrict__ x, const float* __restrict__ wgt,
    unsigned short* __restrict__ out) {
  __shared__ float red[4];
  const int row = blockIdx.x;
  const int tid = threadIdx.x;
  const float* xr = x + (long)row * 2048 + tid * 8;
  const float4 v0 = *(const float4*)(xr);
  const float4 v1 = *(const float4*)(xr + 4);
  float ss = v0.x * v0.x + v0.y * v0.y + v0.z * v0.z + v0.w * v0.w +
             v1.x * v1.x + v1.y * v1.y + v1.z * v1.z + v1.w * v1.w;
#pragma unroll
  for (int off = 1; off < 64; off <<= 1) ss += __shfl_xor(ss, off);
  if ((tid & 63) == 0) red[tid >> 6] = ss;
  __syncthreads();
  float tot = red[0] + red[1] + red[2] + red[3];
  float sc = rsqrtf(tot * (1.0f / 2048.0f) + 1e-5f);
  const float4 w0 = *(const float4*)(wgt + tid * 8);
  const float4 w1 = *(const float4*)(wgt + tid * 8 + 4);
  ushort8 o;
  o[0] = f32_bf16(v0.x * sc * w0.x); o[1] = f32_bf16(v0.y * sc * w0.y);
  o[2] = f32_bf16(v0.z * sc * w0.z); o[3] = f32_bf16(v0.w * sc * w0.w);
  o[4] = f32_bf16(v1.x * sc * w1.x); o[5] = f32_bf16(v1.y * sc * w1.y);
  o[6] = f32_bf16(v1.z * sc * w1.z); o[7] = f32_bf16(v1.w * sc * w1.w);
  *(ushort8*)(out + (long)row * 2048 + tid * 8) = o;
}

// ------------------------------------- BK=32 2-buffer high-occupancy gemm ----
// C[M,N] = A[M,K] @ B[N,K]^T, bf16 in, f32 acc.
// BN=256: 256x256 tile, waves 2Mx4N, per-wave 128x64; LDS 64 KB -> 2 blk/CU.
// BN=128: 256x128 tile, waves 4Mx2N, per-wave 64x64;  LDS 48 KB -> 3 blk/CU.
// TLP is the lever: 4+ waves/SIMD let other blocks' MFMA cover this block's
// LDS drains / barriers (1-block/CU variants all plateaued at ~31% MfmaUtil).
// Stage tile t+1 at TOP of tile t (full tile of flight); vmcnt(loads/tile)
// + barrier before reads (drains only tile t's loads, keeps t+1's in
// flight); end-of-tile barrier for buffer overwrite safety.
// Granule XOR-swizzle (PMC-verified 0 conflicts): LDS slot = g^((row>>1)&3);
// read side per-thread constant, write side via inverse-swizzled GLOBAL
// source; LDS dest stays linear for global_load_lds (rule #21).
// EPI 0: bf16. EPI 1: f32 = res+acc. EPI 2: swiglu on interleaved cols.
template <int BN, int EPI>
__global__ __launch_bounds__(512, 4) void gemm_p(
    const unsigned short* __restrict__ A, const unsigned short* __restrict__ B,
    void* __restrict__ Cout, const float* __restrict__ res, int M, int N, int K) {
  constexpr int MH = (BN == 256) ? 2 : 1;   // m-half phases per tile
  constexpr int MF = MH * 4;                 // m-fragments per wave
  constexpr int BL = (BN == 256) ? 2 : 1;    // B loads/thread/tile
  constexpr int VMN = 2 + BL;                // loads per tile per thread
  __shared__ __align__(16) unsigned short As[2][256 * 32];
  __shared__ __align__(16) unsigned short Bs[2][BN * 32];

  const int tid = threadIdx.x;
  const int lane = tid & 63;
  const int w = tid >> 6;
  const int c = lane & 15, g = lane >> 4;
  const int wm = (BN == 256) ? (w >> 2) * 128 : (w >> 1) * 64;
  const int wn = (BN == 256) ? (w & 3) * 64 : (w & 1) * 64;
  // per-thread constant swizzled granule offset (elements)
  const int gs = ((g ^ ((c >> 1) & 3)) << 3);

  // bijective XCD swizzle (all grids have nwg % 8 == 0)
  const int id = blockIdx.y * gridDim.x + blockIdx.x;
  const int cpx = (gridDim.x * gridDim.y) >> 3;
  const int sid = (id & 7) * cpx + (id >> 3);
  const int bx = sid % gridDim.x;
  const int by = sid / gridDim.x;
  const long m0 = (long)bx * 256;
  const long n0 = (long)by * BN;

  const f32x4 fzero = {0.f, 0.f, 0.f, 0.f};
  f32x4 acc[MF][4];
#pragma unroll
  for (int i = 0; i < MF; ++i)
#pragma unroll
    for (int j = 0; j < 4; ++j) acc[i][j] = fzero;

  auto stageA = [&](int buf, int k0) {  // 2 loads/thread (1024 granules)
#pragma unroll
    for (int q = 0; q < 2; ++q) {
      int G = q * 512 + tid;
      int sg = (G & 3) ^ ((G >> 3) & 3);  // inverse swizzle on global source
      async16(&As[buf][(q * 512 + (tid & ~63)) * 8],
              A + (m0 + (G >> 2)) * (long)K + k0 + sg * 8);
    }
  };
  auto stageB = [&](int buf, int k0) {
#pragma unroll
    for (int q = 0; q < BL; ++q) {
      int G = q * 512 + tid;
      int sg = (G & 3) ^ ((G >> 3) & 3);
      async16(&Bs[buf][(q * 512 + (tid & ~63)) * 8],
              B + (n0 + (G >> 2)) * (long)K + k0 + sg * 8);
    }
  };

  const int NT = K >> 5;
  stageA(0, 0);
  stageB(0, 0);

  for (int t = 0; t < NT; ++t) {
    const int buf = t & 1;
    const bool pf = (t + 1 < NT);
    if (pf) {  // stage t+1 into the other buffer (read-safe: end barrier of
      stageA(buf ^ 1, (t + 1) << 5);  // tile t-1 ended all reads of it)
      stageB(buf ^ 1, (t + 1) << 5);
    }
    if (pf)
      asm volatile("s_waitcnt vmcnt(%0)" ::"i"(VMN) : "memory");
    else
      asm volatile("s_waitcnt vmcnt(0)" ::: "memory");
    __builtin_amdgcn_s_barrier();

    const unsigned short* Ab = As[buf];
    const unsigned short* Bb = Bs[buf];
    bf16x8 bfr[4];
#pragma unroll
    for (int nf = 0; nf < 4; ++nf)
      bfr[nf] = *(const bf16x8*)(Bb + (wn + nf * 16 + c) * 32 + gs);
#pragma unroll
    for (int mh = 0; mh < MH; ++mh) {
      bf16x8 af[4];
#pragma unroll
      for (int mf = 0; mf < 4; ++mf)
        af[mf] = *(const bf16x8*)(Ab + (wm + mh * 64 + mf * 16 + c) * 32 + gs);
      __builtin_amdgcn_s_setprio(1);
#pragma unroll
      for (int mf = 0; mf < 4; ++mf)
#pragma unroll
        for (int nf = 0; nf < 4; ++nf)
          acc[mh * 4 + mf][nf] = __builtin_amdgcn_mfma_f32_16x16x32_bf16(
              af[mf], bfr[nf], acc[mh * 4 + mf][nf], 0, 0, 0);
      __builtin_amdgcn_s_setprio(0);
    }
    __builtin_amdgcn_s_barrier();
  }

#pragma unroll
  for (int i = 0; i < MF; ++i) {
#pragma unroll
    for (int j = 0; j < 4; ++j) {
      const long row0 = m0 + wm + i * 16 + g * 4;
      const long col = n0 + wn + j * 16 + c;
#pragma unroll
      for (int r = 0; r < 4; ++r) {
        float v = acc[i][j][r];
        if (EPI == 0) {
          ((unsigned short*)Cout)[(row0 + r) * N + col] = f32_bf16(v);
        } else if (EPI == 1) {
          ((float*)Cout)[(row0 + r) * N + col] = res[(row0 + r) * N + col] + v;
        } else {
          float other = __shfl_xor(v, 1);
          if (!(c & 1)) {
            float sg2 = v / (1.0f + __expf(-v));
            ((unsigned short*)Cout)[(row0 + r) * (long)(N >> 1) + (col >> 1)] =
                f32_bf16(sg2 * other);
          }
        }
      }
    }
  }
}

// ----------------------------------------------------------- v transpose ----
__global__ __launch_bounds__(256) void transpose_v(
    const unsigned short* __restrict__ qkv, unsigned short* __restrict__ vT) {
  __shared__ __align__(16) unsigned short tile[64][72];
  const int tx = blockIdx.x;
  const int dx = blockIdx.y;
  const int tid = threadIdx.x;
  const int r = tid >> 3, cg = tid & 7;
#pragma unroll
  for (int it = 0; it < 2; ++it) {
    const unsigned short* src =
        qkv + (long)(tx * 64 + r + it * 32) * 3072 + 2560 + dx * 64 + cg * 8;
    *(ushort8*)(&tile[r + it * 32][cg * 8]) = *(const ushort8*)src;
  }
  __syncthreads();
#pragma unroll
  for (int it = 0; it < 2; ++it) {
    int d = r + it * 32;
    ushort8 v;
#pragma unroll
    for (int j = 0; j < 8; ++j) v[j] = tile[cg * 8 + j][d];
    *(ushort8*)(vT + (long)(dx * 64 + d) * 4096 + tx * 64 + cg * 8) = v;
  }
}

// ------------------------------------------------------------- attention ----
// Swapped-operand causal GQA flash attention (see round-1 notes).
__global__ __launch_bounds__(512, 2) void attn_kernel(
    const unsigned short* __restrict__ qkv, const unsigned short* __restrict__ vT,
    unsigned short* __restrict__ y) {
  constexpr float SCL = 0.08838834764831845f * 1.4426950408889634f;
  __shared__ __align__(16) unsigned short Kb[2][64 * 128];
  __shared__ __align__(16) unsigned short Vb[2][128 * 64];

  const int tid = threadIdx.x;
  const int lane = tid & 63;
  const int w = tid >> 6;
  const int c = lane & 15, g = lane >> 4;
  const int h = blockIdx.x >> 4;
  const int pid = blockIdx.x & 15;
  const int kvh = h >> 2;
  const int qt = (w < 4) ? pid : (31 - pid);
  const int q0w = qt * 128 + (w & 3) * 32;
  const int nsteps = 2 * (31 - pid) + 2;

  const f32x4 fzero = {0.f, 0.f, 0.f, 0.f};

  bf16x8 qf[2][4];
#pragma unroll
  for (int mt = 0; mt < 2; ++mt)
#pragma unroll
    for (int kk = 0; kk < 4; ++kk)
      qf[mt][kk] = *(const bf16x8*)(qkv + (long)(q0w + mt * 16 + c) * 3072 +
                                    h * 128 + kk * 32 + g * 8);

  f32x4 o[2][8];
#pragma unroll
  for (int mt = 0; mt < 2; ++mt)
#pragma unroll
    for (int dt = 0; dt < 8; ++dt) o[mt][dt] = fzero;
  float m[2] = {-1e30f, -1e30f}, l[2] = {0.f, 0.f};

  auto stage = [&](int buf, int kv0) {
#pragma unroll
    for (int k = 0; k < 2; ++k) {
      int G = k * 512 + tid;
      int row = G >> 4, colg = (G & 15) ^ (row & 7);
      async16(&Kb[buf][(k * 512 + (tid & ~63)) * 8],
              qkv + (long)(kv0 + row) * 3072 + 2048 + kvh * 128 + colg * 8);
    }
#pragma unroll
    for (int k = 0; k < 2; ++k) {
      int G = k * 512 + tid;
      int row = G >> 3, colg = (G & 7) ^ (row & 7);
      async16(&Vb[buf][(k * 512 + (tid & ~63)) * 8],
              vT + (long)(kvh * 128 + row) * 4096 + kv0 + colg * 8);
    }
  };

  stage(0, 0);
  for (int s = 0; s < nsteps; ++s) {
    const int kv0 = s * 64;
    const int bi = s & 1;
    if (s + 1 < nsteps) {
      stage(bi ^ 1, kv0 + 64);
      asm volatile("s_waitcnt vmcnt(4)" ::: "memory");
    } else {
      asm volatile("s_waitcnt vmcnt(0)" ::: "memory");
    }
    __builtin_amdgcn_s_barrier();
    if (kv0 <= q0w + 31) {
      const unsigned short* Ks = Kb[bi];
      const unsigned short* Vs = Vb[bi];
      f32x4 sv[2][4];
#pragma unroll
      for (int mt = 0; mt < 2; ++mt)
#pragma unroll
        for (int nt = 0; nt < 4; ++nt) sv[mt][nt] = fzero;
#pragma unroll
      for (int kk = 0; kk < 4; ++kk) {
        bf16x8 kf[4];
#pragma unroll
        for (int nt = 0; nt < 4; ++nt)
          kf[nt] = *(const bf16x8*)(Ks + (nt * 16 + c) * 128 +
                                    (((kk * 4 + g) ^ (c & 7)) << 3));
#pragma unroll
        for (int mt = 0; mt < 2; ++mt)
#pragma unroll
          for (int nt = 0; nt < 4; ++nt)
            sv[mt][nt] = __builtin_amdgcn_mfma_f32_16x16x32_bf16(
                kf[nt], qf[mt][kk], sv[mt][nt], 0, 0, 0);
      }
      const bool need_mask = (kv0 + 63 > q0w);
      float al[2];
#pragma unroll
      for (int mt = 0; mt < 2; ++mt) {
        const int qrow = q0w + mt * 16 + c;
#pragma unroll
        for (int nt = 0; nt < 4; ++nt)
#pragma unroll
          for (int r = 0; r < 4; ++r) {
            float xx = sv[mt][nt][r] * SCL;
            if (need_mask && (kv0 + nt * 16 + g * 4 + r > qrow)) xx = -3.0e38f;
            sv[mt][nt][r] = xx;
          }
        float mx = -3.0e38f;
#pragma unroll
        for (int nt = 0; nt < 4; ++nt)
#pragma unroll
          for (int r = 0; r < 4; ++r) mx = fmaxf(mx, sv[mt][nt][r]);
        mx = fmaxf(mx, __shfl_xor(mx, 16));
        mx = fmaxf(mx, __shfl_xor(mx, 32));
        const float mn = fmaxf(m[mt], mx);
        const float a = exp2f(m[mt] - mn);
        m[mt] = mn;
        al[mt] = a;
        float rs = 0.f;
#pragma unroll
        for (int nt = 0; nt < 4; ++nt)
#pragma unroll
          for (int r = 0; r < 4; ++r) {
            float p = exp2f(sv[mt][nt][r] - mn);
            sv[mt][nt][r] = p;
            rs += p;
          }
        rs += __shfl_xor(rs, 16);
        rs += __shfl_xor(rs, 32);
        l[mt] = l[mt] * a + rs;
#pragma unroll
        for (int dt = 0; dt < 8; ++dt) o[mt][dt] *= al[mt];
      }
#pragma unroll
      for (int nt = 0; nt < 4; ++nt) {
        bf16x4 pb[2];
#pragma unroll
        for (int mt = 0; mt < 2; ++mt) {
          int lo_, hi_;
          float s0 = sv[mt][nt][0], s1 = sv[mt][nt][1];
          float s2 = sv[mt][nt][2], s3 = sv[mt][nt][3];
          asm("v_cvt_pk_bf16_f32 %0, %1, %2" : "=v"(lo_) : "v"(s0), "v"(s1));
          asm("v_cvt_pk_bf16_f32 %0, %1, %2" : "=v"(hi_) : "v"(s2), "v"(s3));
          int2 pk = make_int2(lo_, hi_);
          pb[mt] = __builtin_bit_cast(bf16x4, pk);
        }
#pragma unroll
        for (int dt = 0; dt < 8; ++dt) {
          bf16x4 vt = *(const bf16x4*)(Vs + (dt * 16 + c) * 64 +
                                       (((nt * 2 + (g >> 1)) ^ (c & 7)) << 3) +
                                       (g & 1) * 4);
          o[0][dt] = mfma16(vt, pb[0], o[0][dt]);
          o[1][dt] = mfma16(vt, pb[1], o[1][dt]);
        }
      }
    }
    __builtin_amdgcn_s_barrier();
  }
#pragma unroll
  for (int mt = 0; mt < 2; ++mt) {
    const float inv = 1.0f / l[mt];
    const long qrow = q0w + mt * 16 + c;
#pragma unroll
    for (int dt = 0; dt < 8; ++dt) {
      us4 st;
      st[0] = f32_bf16(o[mt][dt][0] * inv);
      st[1] = f32_bf16(o[mt][dt][1] * inv);
      st[2] = f32_bf16(o[mt][dt][2] * inv);
      st[3] = f32_bf16(o[mt][dt][3] * inv);
      *(us4*)(y + qrow * 2048 + h * 128 + dt * 16 + g * 4) = st;
    }
  }
}

// ------------------------------------------------------------------ host ----
extern "C" void kernel_launch(void* const* d_in, const int* in_sizes, int n_in,
                              void* d_out, int out_size, void* d_ws, size_t ws_size,
                              hipStream_t stream) {
  (void)in_sizes; (void)n_in; (void)out_size; (void)ws_size;
  const float* x      = (const float*)d_in[0];
  const float* attn_w = (const float*)d_in[2];
  const float* wq     = (const float*)d_in[3];
  const float* wk     = (const float*)d_in[4];
  const float* wv     = (const float*)d_in[5];
  const float* wo     = (const float*)d_in[6];
  const float* ffn_w  = (const float*)d_in[7];
  const float* wg     = (const float*)d_in[8];
  const float* wu     = (const float*)d_in[9];
  const float* wd     = (const float*)d_in[10];
  float* out = (float*)d_out;

  char* ws = (char*)d_ws;
  size_t off = 0;
  auto alloc = [&](size_t bytes) {
    char* p = ws + off;
    off += (bytes + 255) & ~(size_t)255;
    return p;
  };
  float2* rope_tab        = (float2*)alloc(4096UL * 64 * sizeof(float2));
  unsigned short* wqkv_b  = (unsigned short*)alloc(3072UL * 2048 * 2);
  unsigned short* wo_b    = (unsigned short*)alloc(2048UL * 2048 * 2);
  unsigned short* wgu_b   = (unsigned short*)alloc(16384UL * 2048 * 2);
  unsigned short* wd_b    = (unsigned short*)alloc(2048UL * 8192 * 2);
  unsigned short* h_b     = (unsigned short*)alloc(4096UL * 2048 * 2);
  unsigned short* qkv_b   = (unsigned short*)alloc(4096UL * 3072 * 2);
  unsigned short* vT_b    = (unsigned short*)alloc(512UL * 4096 * 2);
  unsigned short* y_b     = (unsigned short*)alloc(4096UL * 2048 * 2);
  float* r1               = (float*)alloc(4096UL * 2048 * 4);
  unsigned short* t_b     = (unsigned short*)alloc(4096UL * 8192 * 2);

  // weight casts
  cast_bf16_kernel<<<2048, 256, 0, stream>>>(wq, wqkv_b, 524288);
  cast_bf16_kernel<<<512, 256, 0, stream>>>(wk, wqkv_b + 2048L * 2048, 131072);
  cast_bf16_kernel<<<512, 256, 0, stream>>>(wv, wqkv_b + 2560L * 2048, 131072);
  cast_bf16_kernel<<<2048, 256, 0, stream>>>(wo, wo_b, 524288);
  cast_gu_kernel<<<16384, 256, 0, stream>>>(wg, wu, wgu_b);
  cast_bf16_kernel<<<8192, 256, 0, stream>>>(wd, wd_b, 2097152);
  rope_table_kernel<<<1024, 256, 0, stream>>>(rope_tab);

  // attn branch
  rmsnorm_kernel<<<4096, 256, 0, stream>>>(x, attn_w, h_b);
  {
    dim3 grid(16, 12);
    gemm_p<256, 0><<<grid, 512, 0, stream>>>(h_b, wqkv_b, qkv_b, nullptr, 4096, 3072, 2048);
  }
  rope_apply_kernel<<<4096, 256, 0, stream>>>(qkv_b, rope_tab);
  {
    dim3 grid(64, 8);
    transpose_v<<<grid, 256, 0, stream>>>(qkv_b, vT_b);
  }
  attn_kernel<<<256, 512, 0, stream>>>(qkv_b, vT_b, y_b);
  {
    dim3 grid(16, 16);
    gemm_p<128, 1><<<grid, 512, 0, stream>>>(y_b, wo_b, r1, x, 4096, 2048, 2048);
  }

  // ffn branch
  rmsnorm_kernel<<<4096, 256, 0, stream>>>(r1, ffn_w, h_b);
  {
    dim3 grid(16, 64);
    gemm_p<256, 2><<<grid, 512, 0, stream>>>(h_b, wgu_b, t_b, nullptr, 4096, 16384, 2048);
  }
  {
    dim3 grid(16, 16);
    gemm_p<128, 1><<<grid, 512, 0, stream>>>(t_b, wd_b, out, r1, 4096, 2048, 8192);
  }
}

// Round 12
// 967.953 us; speedup vs baseline: 3.4684x; 3.4684x over previous
//
#include <hip/hip_runtime.h>
#include <math.h>

#define DEVI static __device__ __forceinline__

typedef __attribute__((ext_vector_type(8))) short bf16x8;
typedef __attribute__((ext_vector_type(4))) short bf16x4;
typedef __attribute__((ext_vector_type(8))) unsigned short ushort8;
typedef __attribute__((ext_vector_type(4))) unsigned short us4;
typedef __attribute__((ext_vector_type(4))) float f32x4;

DEVI unsigned short f32_bf16(float f) {
  unsigned int u = __float_as_uint(f);
  u += 0x7fffu + ((u >> 16) & 1u);
  return (unsigned short)(u >> 16);
}
DEVI float bf16_f32(unsigned short h) {
  return __uint_as_float(((unsigned int)h) << 16);
}

DEVI void async16(void* lds, const void* g) {
  __builtin_amdgcn_global_load_lds(
      (const __attribute__((address_space(1))) void*)g,
      (__attribute__((address_space(3))) void*)lds,
      16, 0, 0);
}

#if __has_builtin(__builtin_amdgcn_mfma_f32_16x16x16bf16_1k)
DEVI f32x4 mfma16(bf16x4 a, bf16x4 b, f32x4 c) {
  return __builtin_amdgcn_mfma_f32_16x16x16bf16_1k(a, b, c, 0, 0, 0);
}
#else
DEVI f32x4 mfma16(bf16x4 a, bf16x4 b, f32x4 c) {
  asm volatile("v_mfma_f32_16x16x16_bf16 %0, %1, %2, %0" : "+v"(c) : "v"(a), "v"(b));
  return c;
}
#endif

// ---------------------------------------------------------------- casts ----
__global__ __launch_bounds__(256) void cast_bf16_kernel(
    const float* __restrict__ src, unsigned short* __restrict__ dst, long n8) {
  long i = (long)blockIdx.x * 256 + threadIdx.x;
  if (i >= n8) return;
  const float4 a = *(const float4*)(src + i * 8);
  const float4 b = *(const float4*)(src + i * 8 + 4);
  ushort8 o;
  o[0] = f32_bf16(a.x); o[1] = f32_bf16(a.y); o[2] = f32_bf16(a.z); o[3] = f32_bf16(a.w);
  o[4] = f32_bf16(b.x); o[5] = f32_bf16(b.y); o[6] = f32_bf16(b.z); o[7] = f32_bf16(b.w);
  *(ushort8*)(dst + i * 8) = o;
}

// gate/up interleave: dst row 2j = gate j, row 2j+1 = up j.  [16384][2048]
__global__ __launch_bounds__(256) void cast_gu_kernel(
    const float* __restrict__ gate, const float* __restrict__ up,
    unsigned short* __restrict__ dst) {
  long i = (long)blockIdx.x * 256 + threadIdx.x;
  long row = i >> 8;
  long col = (i & 255) * 8;
  const float* src = ((row & 1) ? up : gate) + ((row >> 1) << 11) + col;
  const float4 a = *(const float4*)(src);
  const float4 b = *(const float4*)(src + 4);
  ushort8 o;
  o[0] = f32_bf16(a.x); o[1] = f32_bf16(a.y); o[2] = f32_bf16(a.z); o[3] = f32_bf16(a.w);
  o[4] = f32_bf16(b.x); o[5] = f32_bf16(b.y); o[6] = f32_bf16(b.z); o[7] = f32_bf16(b.w);
  *(ushort8*)(dst + i * 8) = o;
}

// ----------------------------------------------------------------- rope ----
__global__ __launch_bounds__(256) void rope_table_kernel(float2* __restrict__ tab) {
  int idx = blockIdx.x * 256 + threadIdx.x;
  int t = idx >> 6, i = idx & 63;
  float inv = __expf(-(float)(2 * i) * (1.0f / 128.0f) * 13.122363377404328f);
  float f = (float)t * inv;
  tab[idx] = make_float2(cosf(f), sinf(f));
}

__global__ __launch_bounds__(256) void rope_apply_kernel(
    unsigned short* __restrict__ qkv, const float2* __restrict__ tab) {
  const int row = blockIdx.x;
  const int tid = threadIdx.x;
#pragma unroll
  for (int it = 0; it < 5; ++it) {
    int p = tid + it * 256;
    int head = p >> 6, i = p & 63;
    int col = (p < 1024) ? (head * 128 + 2 * i) : (2048 + (head - 16) * 128 + 2 * i);
    unsigned short* ptr = qkv + (long)row * 3072 + col;
    float a = bf16_f32(ptr[0]), b = bf16_f32(ptr[1]);
    float2 cs = tab[row * 64 + i];
    float a2 = a * cs.x - b * cs.y;
    float b2 = a * cs.y + b * cs.x;
    ptr[0] = f32_bf16(a2);
    ptr[1] = f32_bf16(b2);
  }
}

// -------------------------------------------------------------- rmsnorm ----
__global__ __launch_bounds__(256) void rmsnorm_kernel(
    const float* __restrict__ x, const float* __restrict__ wgt,
    unsigned short* __restrict__ out) {
  __shared__ float red[4];
  const int row = blockIdx.x;
  const int tid = threadIdx.x;
  const float* xr = x + (long)row * 2048 + tid * 8;
  const float4 v0 = *(const float4*)(xr);
  const float4 v1 = *(const float4*)(xr + 4);
  float ss = v0.x * v0.x + v0.y * v0.y + v0.z * v0.z + v0.w * v0.w +
             v1.x * v1.x + v1.y * v1.y + v1.z * v1.z + v1.w * v1.w;
#pragma unroll
  for (int off = 1; off < 64; off <<= 1) ss += __shfl_xor(ss, off);
  if ((tid & 63) == 0) red[tid >> 6] = ss;
  __syncthreads();
  float tot = red[0] + red[1] + red[2] + red[3];
  float sc = rsqrtf(tot * (1.0f / 2048.0f) + 1e-5f);
  const float4 w0 = *(const float4*)(wgt + tid * 8);
  const float4 w1 = *(const float4*)(wgt + tid * 8 + 4);
  ushort8 o;
  o[0] = f32_bf16(v0.x * sc * w0.x); o[1] = f32_bf16(v0.y * sc * w0.y);
  o[2] = f32_bf16(v0.z * sc * w0.z); o[3] = f32_bf16(v0.w * sc * w0.w);
  o[4] = f32_bf16(v1.x * sc * w1.x); o[5] = f32_bf16(v1.y * sc * w1.y);
  o[6] = f32_bf16(v1.z * sc * w1.z); o[7] = f32_bf16(v1.w * sc * w1.w);
  *(ushort8*)(out + (long)row * 2048 + tid * 8) = o;
}

// --------------------------- BK=32 2-buffer high-occupancy gemm (no spill) ----
// C[M,N] = A[M,K] @ B[N,K]^T, bf16 in, f32 acc. 8 waves, per-wave 64x64
// output (acc[4][4] = 64 VGPR; total ~110 < 128 cap -> NO spill at 4
// waves/SIMD). BM x BN = 128x256 (2Mx4N) or 256x128 (4Mx2N). LDS 48 KB ->
// 2-3 blocks/CU: TLP from independent co-resident blocks covers barrier /
// vmcnt drains that pinned all 1-block/CU variants at ~31% MfmaUtil.
// Stage tile t+1 at TOP of tile t; vmcnt(loads/tile) keeps t+1's loads in
// flight while draining t's; end-of-tile barrier = overwrite safety.
// Granule XOR-swizzle (PMC-verified 0 conflicts): LDS slot = g^((row>>1)&3);
// read side per-thread constant, write side via inverse-swizzled GLOBAL
// source; LDS dest stays linear for global_load_lds (rule #21).
// EPI 0: bf16. EPI 1: f32 = res+acc. EPI 2: swiglu on interleaved cols.
template <int BM, int BN, int EPI>
__global__ __launch_bounds__(512, 4) void gemm_p(
    const unsigned short* __restrict__ A, const unsigned short* __restrict__ B,
    void* __restrict__ Cout, const float* __restrict__ res, int M, int N, int K) {
  constexpr int AL = BM / 128;   // A loads/thread/tile
  constexpr int BL = BN / 128;   // B loads/thread/tile
  constexpr int VMN = AL + BL;   // loads per tile per thread
  constexpr int NN = BN / 64;    // n wave-groups
  __shared__ __align__(16) unsigned short As[2][BM * 32];
  __shared__ __align__(16) unsigned short Bs[2][BN * 32];

  const int tid = threadIdx.x;
  const int lane = tid & 63;
  const int w = tid >> 6;
  const int c = lane & 15, g = lane >> 4;
  const int wm = (w / NN) * 64;
  const int wn = (w % NN) * 64;
  // per-thread constant swizzled granule offset (elements)
  const int gs = ((g ^ ((c >> 1) & 3)) << 3);

  // bijective XCD swizzle (all grids have nwg % 8 == 0)
  const int id = blockIdx.y * gridDim.x + blockIdx.x;
  const int cpx = (gridDim.x * gridDim.y) >> 3;
  const int sid = (id & 7) * cpx + (id >> 3);
  const int bx = sid % gridDim.x;
  const int by = sid / gridDim.x;
  const long m0 = (long)bx * BM;
  const long n0 = (long)by * BN;

  const f32x4 fzero = {0.f, 0.f, 0.f, 0.f};
  f32x4 acc[4][4];
#pragma unroll
  for (int i = 0; i < 4; ++i)
#pragma unroll
    for (int j = 0; j < 4; ++j) acc[i][j] = fzero;

  auto stageA = [&](int buf, int k0) {
#pragma unroll
    for (int q = 0; q < AL; ++q) {
      int G = q * 512 + tid;
      int sg = (G & 3) ^ ((G >> 3) & 3);  // inverse swizzle on global source
      async16(&As[buf][(q * 512 + (tid & ~63)) * 8],
              A + (m0 + (G >> 2)) * (long)K + k0 + sg * 8);
    }
  };
  auto stageB = [&](int buf, int k0) {
#pragma unroll
    for (int q = 0; q < BL; ++q) {
      int G = q * 512 + tid;
      int sg = (G & 3) ^ ((G >> 3) & 3);
      async16(&Bs[buf][(q * 512 + (tid & ~63)) * 8],
              B + (n0 + (G >> 2)) * (long)K + k0 + sg * 8);
    }
  };

  const int NT = K >> 5;
  stageA(0, 0);
  stageB(0, 0);

  for (int t = 0; t < NT; ++t) {
    const int buf = t & 1;
    const bool pf = (t + 1 < NT);
    if (pf) {  // stage t+1 (buffer was fully read by end-barrier of t-1)
      stageA(buf ^ 1, (t + 1) << 5);
      stageB(buf ^ 1, (t + 1) << 5);
    }
    if (pf)
      asm volatile("s_waitcnt vmcnt(%0)" ::"i"(VMN) : "memory");
    else
      asm volatile("s_waitcnt vmcnt(0)" ::: "memory");
    __builtin_amdgcn_s_barrier();

    const unsigned short* Ab = As[buf];
    const unsigned short* Bb = Bs[buf];
    bf16x8 af[4], bfr[4];
#pragma unroll
    for (int nf = 0; nf < 4; ++nf)
      bfr[nf] = *(const bf16x8*)(Bb + (wn + nf * 16 + c) * 32 + gs);
#pragma unroll
    for (int mf = 0; mf < 4; ++mf)
      af[mf] = *(const bf16x8*)(Ab + (wm + mf * 16 + c) * 32 + gs);
    __builtin_amdgcn_s_setprio(1);
#pragma unroll
    for (int mf = 0; mf < 4; ++mf)
#pragma unroll
      for (int nf = 0; nf < 4; ++nf)
        acc[mf][nf] = __builtin_amdgcn_mfma_f32_16x16x32_bf16(
            af[mf], bfr[nf], acc[mf][nf], 0, 0, 0);
    __builtin_amdgcn_s_setprio(0);
    __builtin_amdgcn_s_barrier();
  }

#pragma unroll
  for (int i = 0; i < 4; ++i) {
#pragma unroll
    for (int j = 0; j < 4; ++j) {
      const long row0 = m0 + wm + i * 16 + g * 4;
      const long col = n0 + wn + j * 16 + c;
#pragma unroll
      for (int r = 0; r < 4; ++r) {
        float v = acc[i][j][r];
        if (EPI == 0) {
          ((unsigned short*)Cout)[(row0 + r) * N + col] = f32_bf16(v);
        } else if (EPI == 1) {
          ((float*)Cout)[(row0 + r) * N + col] = res[(row0 + r) * N + col] + v;
        } else {
          float other = __shfl_xor(v, 1);
          if (!(c & 1)) {
            float sg2 = v / (1.0f + __expf(-v));
            ((unsigned short*)Cout)[(row0 + r) * (long)(N >> 1) + (col >> 1)] =
                f32_bf16(sg2 * other);
          }
        }
      }
    }
  }
}

// ----------------------------------------------------------- v transpose ----
__global__ __launch_bounds__(256) void transpose_v(
    const unsigned short* __restrict__ qkv, unsigned short* __restrict__ vT) {
  __shared__ __align__(16) unsigned short tile[64][72];
  const int tx = blockIdx.x;
  const int dx = blockIdx.y;
  const int tid = threadIdx.x;
  const int r = tid >> 3, cg = tid & 7;
#pragma unroll
  for (int it = 0; it < 2; ++it) {
    const unsigned short* src =
        qkv + (long)(tx * 64 + r + it * 32) * 3072 + 2560 + dx * 64 + cg * 8;
    *(ushort8*)(&tile[r + it * 32][cg * 8]) = *(const ushort8*)src;
  }
  __syncthreads();
#pragma unroll
  for (int it = 0; it < 2; ++it) {
    int d = r + it * 32;
    ushort8 v;
#pragma unroll
    for (int j = 0; j < 8; ++j) v[j] = tile[cg * 8 + j][d];
    *(ushort8*)(vT + (long)(dx * 64 + d) * 4096 + tx * 64 + cg * 8) = v;
  }
}

// ------------------------------------------------------------- attention ----
// Swapped-operand causal GQA flash attention (see round-1 notes).
__global__ __launch_bounds__(512, 2) void attn_kernel(
    const unsigned short* __restrict__ qkv, const unsigned short* __restrict__ vT,
    unsigned short* __restrict__ y) {
  constexpr float SCL = 0.08838834764831845f * 1.4426950408889634f;
  __shared__ __align__(16) unsigned short Kb[2][64 * 128];
  __shared__ __align__(16) unsigned short Vb[2][128 * 64];

  const int tid = threadIdx.x;
  const int lane = tid & 63;
  const int w = tid >> 6;
  const int c = lane & 15, g = lane >> 4;
  const int h = blockIdx.x >> 4;
  const int pid = blockIdx.x & 15;
  const int kvh = h >> 2;
  const int qt = (w < 4) ? pid : (31 - pid);
  const int q0w = qt * 128 + (w & 3) * 32;
  const int nsteps = 2 * (31 - pid) + 2;

  const f32x4 fzero = {0.f, 0.f, 0.f, 0.f};

  bf16x8 qf[2][4];
#pragma unroll
  for (int mt = 0; mt < 2; ++mt)
#pragma unroll
    for (int kk = 0; kk < 4; ++kk)
      qf[mt][kk] = *(const bf16x8*)(qkv + (long)(q0w + mt * 16 + c) * 3072 +
                                    h * 128 + kk * 32 + g * 8);

  f32x4 o[2][8];
#pragma unroll
  for (int mt = 0; mt < 2; ++mt)
#pragma unroll
    for (int dt = 0; dt < 8; ++dt) o[mt][dt] = fzero;
  float m[2] = {-1e30f, -1e30f}, l[2] = {0.f, 0.f};

  auto stage = [&](int buf, int kv0) {
#pragma unroll
    for (int k = 0; k < 2; ++k) {
      int G = k * 512 + tid;
      int row = G >> 4, colg = (G & 15) ^ (row & 7);
      async16(&Kb[buf][(k * 512 + (tid & ~63)) * 8],
              qkv + (long)(kv0 + row) * 3072 + 2048 + kvh * 128 + colg * 8);
    }
#pragma unroll
    for (int k = 0; k < 2; ++k) {
      int G = k * 512 + tid;
      int row = G >> 3, colg = (G & 7) ^ (row & 7);
      async16(&Vb[buf][(k * 512 + (tid & ~63)) * 8],
              vT + (long)(kvh * 128 + row) * 4096 + kv0 + colg * 8);
    }
  };

  stage(0, 0);
  for (int s = 0; s < nsteps; ++s) {
    const int kv0 = s * 64;
    const int bi = s & 1;
    if (s + 1 < nsteps) {
      stage(bi ^ 1, kv0 + 64);
      asm volatile("s_waitcnt vmcnt(4)" ::: "memory");
    } else {
      asm volatile("s_waitcnt vmcnt(0)" ::: "memory");
    }
    __builtin_amdgcn_s_barrier();
    if (kv0 <= q0w + 31) {
      const unsigned short* Ks = Kb[bi];
      const unsigned short* Vs = Vb[bi];
      f32x4 sv[2][4];
#pragma unroll
      for (int mt = 0; mt < 2; ++mt)
#pragma unroll
        for (int nt = 0; nt < 4; ++nt) sv[mt][nt] = fzero;
#pragma unroll
      for (int kk = 0; kk < 4; ++kk) {
        bf16x8 kf[4];
#pragma unroll
        for (int nt = 0; nt < 4; ++nt)
          kf[nt] = *(const bf16x8*)(Ks + (nt * 16 + c) * 128 +
                                    (((kk * 4 + g) ^ (c & 7)) << 3));
#pragma unroll
        for (int mt = 0; mt < 2; ++mt)
#pragma unroll
          for (int nt = 0; nt < 4; ++nt)
            sv[mt][nt] = __builtin_amdgcn_mfma_f32_16x16x32_bf16(
                kf[nt], qf[mt][kk], sv[mt][nt], 0, 0, 0);
      }
      const bool need_mask = (kv0 + 63 > q0w);
      float al[2];
#pragma unroll
      for (int mt = 0; mt < 2; ++mt) {
        const int qrow = q0w + mt * 16 + c;
#pragma unroll
        for (int nt = 0; nt < 4; ++nt)
#pragma unroll
          for (int r = 0; r < 4; ++r) {
            float xx = sv[mt][nt][r] * SCL;
            if (need_mask && (kv0 + nt * 16 + g * 4 + r > qrow)) xx = -3.0e38f;
            sv[mt][nt][r] = xx;
          }
        float mx = -3.0e38f;
#pragma unroll
        for (int nt = 0; nt < 4; ++nt)
#pragma unroll
          for (int r = 0; r < 4; ++r) mx = fmaxf(mx, sv[mt][nt][r]);
        mx = fmaxf(mx, __shfl_xor(mx, 16));
        mx = fmaxf(mx, __shfl_xor(mx, 32));
        const float mn = fmaxf(m[mt], mx);
        const float a = exp2f(m[mt] - mn);
        m[mt] = mn;
        al[mt] = a;
        float rs = 0.f;
#pragma unroll
        for (int nt = 0; nt < 4; ++nt)
#pragma unroll
          for (int r = 0; r < 4; ++r) {
            float p = exp2f(sv[mt][nt][r] - mn);
            sv[mt][nt][r] = p;
            rs += p;
          }
        rs += __shfl_xor(rs, 16);
        rs += __shfl_xor(rs, 32);
        l[mt] = l[mt] * a + rs;
#pragma unroll
        for (int dt = 0; dt < 8; ++dt) o[mt][dt] *= al[mt];
      }
#pragma unroll
      for (int nt = 0; nt < 4; ++nt) {
        bf16x4 pb[2];
#pragma unroll
        for (int mt = 0; mt < 2; ++mt) {
          int lo_, hi_;
          float s0 = sv[mt][nt][0], s1 = sv[mt][nt][1];
          float s2 = sv[mt][nt][2], s3 = sv[mt][nt][3];
          asm("v_cvt_pk_bf16_f32 %0, %1, %2" : "=v"(lo_) : "v"(s0), "v"(s1));
          asm("v_cvt_pk_bf16_f32 %0, %1, %2" : "=v"(hi_) : "v"(s2), "v"(s3));
          int2 pk = make_int2(lo_, hi_);
          pb[mt] = __builtin_bit_cast(bf16x4, pk);
        }
#pragma unroll
        for (int dt = 0; dt < 8; ++dt) {
          bf16x4 vt = *(const bf16x4*)(Vs + (dt * 16 + c) * 64 +
                                       (((nt * 2 + (g >> 1)) ^ (c & 7)) << 3) +
                                       (g & 1) * 4);
          o[0][dt] = mfma16(vt, pb[0], o[0][dt]);
          o[1][dt] = mfma16(vt, pb[1], o[1][dt]);
        }
      }
    }
    __builtin_amdgcn_s_barrier();
  }
#pragma unroll
  for (int mt = 0; mt < 2; ++mt) {
    const float inv = 1.0f / l[mt];
    const long qrow = q0w + mt * 16 + c;
#pragma unroll
    for (int dt = 0; dt < 8; ++dt) {
      us4 st;
      st[0] = f32_bf16(o[mt][dt][0] * inv);
      st[1] = f32_bf16(o[mt][dt][1] * inv);
      st[2] = f32_bf16(o[mt][dt][2] * inv);
      st[3] = f32_bf16(o[mt][dt][3] * inv);
      *(us4*)(y + qrow * 2048 + h * 128 + dt * 16 + g * 4) = st;
    }
  }
}

// ------------------------------------------------------------------ host ----
extern "C" void kernel_launch(void* const* d_in, const int* in_sizes, int n_in,
                              void* d_out, int out_size, void* d_ws, size_t ws_size,
                              hipStream_t stream) {
  (void)in_sizes; (void)n_in; (void)out_size; (void)ws_size;
  const float* x      = (const float*)d_in[0];
  const float* attn_w = (const float*)d_in[2];
  const float* wq     = (const float*)d_in[3];
  const float* wk     = (const float*)d_in[4];
  const float* wv     = (const float*)d_in[5];
  const float* wo     = (const float*)d_in[6];
  const float* ffn_w  = (const float*)d_in[7];
  const float* wg     = (const float*)d_in[8];
  const float* wu     = (const float*)d_in[9];
  const float* wd     = (const float*)d_in[10];
  float* out = (float*)d_out;

  char* ws = (char*)d_ws;
  size_t off = 0;
  auto alloc = [&](size_t bytes) {
    char* p = ws + off;
    off += (bytes + 255) & ~(size_t)255;
    return p;
  };
  float2* rope_tab        = (float2*)alloc(4096UL * 64 * sizeof(float2));
  unsigned short* wqkv_b  = (unsigned short*)alloc(3072UL * 2048 * 2);
  unsigned short* wo_b    = (unsigned short*)alloc(2048UL * 2048 * 2);
  unsigned short* wgu_b   = (unsigned short*)alloc(16384UL * 2048 * 2);
  unsigned short* wd_b    = (unsigned short*)alloc(2048UL * 8192 * 2);
  unsigned short* h_b     = (unsigned short*)alloc(4096UL * 2048 * 2);
  unsigned short* qkv_b   = (unsigned short*)alloc(4096UL * 3072 * 2);
  unsigned short* vT_b    = (unsigned short*)alloc(512UL * 4096 * 2);
  unsigned short* y_b     = (unsigned short*)alloc(4096UL * 2048 * 2);
  float* r1               = (float*)alloc(4096UL * 2048 * 4);
  unsigned short* t_b     = (unsigned short*)alloc(4096UL * 8192 * 2);

  // weight casts
  cast_bf16_kernel<<<2048, 256, 0, stream>>>(wq, wqkv_b, 524288);
  cast_bf16_kernel<<<512, 256, 0, stream>>>(wk, wqkv_b + 2048L * 2048, 131072);
  cast_bf16_kernel<<<512, 256, 0, stream>>>(wv, wqkv_b + 2560L * 2048, 131072);
  cast_bf16_kernel<<<2048, 256, 0, stream>>>(wo, wo_b, 524288);
  cast_gu_kernel<<<16384, 256, 0, stream>>>(wg, wu, wgu_b);
  cast_bf16_kernel<<<8192, 256, 0, stream>>>(wd, wd_b, 2097152);
  rope_table_kernel<<<1024, 256, 0, stream>>>(rope_tab);

  // attn branch
  rmsnorm_kernel<<<4096, 256, 0, stream>>>(x, attn_w, h_b);
  {
    dim3 grid(32, 12);
    gemm_p<128, 256, 0><<<grid, 512, 0, stream>>>(h_b, wqkv_b, qkv_b, nullptr, 4096, 3072, 2048);
  }
  rope_apply_kernel<<<4096, 256, 0, stream>>>(qkv_b, rope_tab);
  {
    dim3 grid(64, 8);
    transpose_v<<<grid, 256, 0, stream>>>(qkv_b, vT_b);
  }
  attn_kernel<<<256, 512, 0, stream>>>(qkv_b, vT_b, y_b);
  {
    dim3 grid(16, 16);
    gemm_p<256, 128, 1><<<grid, 512, 0, stream>>>(y_b, wo_b, r1, x, 4096, 2048, 2048);
  }

  // ffn branch
  rmsnorm_kernel<<<4096, 256, 0, stream>>>(r1, ffn_w, h_b);
  {
    dim3 grid(32, 64);
    gemm_p<128, 256, 2><<<grid, 512, 0, stream>>>(h_b, wgu_b, t_b, nullptr, 4096, 16384, 2048);
  }
  {
    dim3 grid(16, 16);
    gemm_p<256, 128, 1><<<grid, 512, 0, stream>>>(t_b, wd_b, out, r1, 4096, 2048, 8192);
  }
}

// Round 13
// 895.597 us; speedup vs baseline: 3.7486x; 1.0808x over previous
//
#include <hip/hip_runtime.h>
#include <math.h>

#define DEVI static __device__ __forceinline__

typedef __attribute__((ext_vector_type(8))) short bf16x8;
typedef __attribute__((ext_vector_type(4))) short bf16x4;
typedef __attribute__((ext_vector_type(8))) unsigned short ushort8;
typedef __attribute__((ext_vector_type(4))) unsigned short us4;
typedef __attribute__((ext_vector_type(4))) float f32x4;

DEVI unsigned short f32_bf16(float f) {
  unsigned int u = __float_as_uint(f);
  u += 0x7fffu + ((u >> 16) & 1u);
  return (unsigned short)(u >> 16);
}
DEVI float bf16_f32(unsigned short h) {
  return __uint_as_float(((unsigned int)h) << 16);
}

DEVI void async16(void* lds, const void* g) {
  __builtin_amdgcn_global_load_lds(
      (const __attribute__((address_space(1))) void*)g,
      (__attribute__((address_space(3))) void*)lds,
      16, 0, 0);
}

#if __has_builtin(__builtin_amdgcn_mfma_f32_16x16x16bf16_1k)
DEVI f32x4 mfma16(bf16x4 a, bf16x4 b, f32x4 c) {
  return __builtin_amdgcn_mfma_f32_16x16x16bf16_1k(a, b, c, 0, 0, 0);
}
#else
DEVI f32x4 mfma16(bf16x4 a, bf16x4 b, f32x4 c) {
  asm volatile("v_mfma_f32_16x16x16_bf16 %0, %1, %2, %0" : "+v"(c) : "v"(a), "v"(b));
  return c;
}
#endif

// ---------------------------------------------------------------- casts ----
__global__ __launch_bounds__(256) void cast_bf16_kernel(
    const float* __restrict__ src, unsigned short* __restrict__ dst, long n8) {
  long i = (long)blockIdx.x * 256 + threadIdx.x;
  if (i >= n8) return;
  const float4 a = *(const float4*)(src + i * 8);
  const float4 b = *(const float4*)(src + i * 8 + 4);
  ushort8 o;
  o[0] = f32_bf16(a.x); o[1] = f32_bf16(a.y); o[2] = f32_bf16(a.z); o[3] = f32_bf16(a.w);
  o[4] = f32_bf16(b.x); o[5] = f32_bf16(b.y); o[6] = f32_bf16(b.z); o[7] = f32_bf16(b.w);
  *(ushort8*)(dst + i * 8) = o;
}

// gate/up interleave: dst row 2j = gate j, row 2j+1 = up j.  [16384][2048]
__global__ __launch_bounds__(256) void cast_gu_kernel(
    const float* __restrict__ gate, const float* __restrict__ up,
    unsigned short* __restrict__ dst) {
  long i = (long)blockIdx.x * 256 + threadIdx.x;
  long row = i >> 8;
  long col = (i & 255) * 8;
  const float* src = ((row & 1) ? up : gate) + ((row >> 1) << 11) + col;
  const float4 a = *(const float4*)(src);
  const float4 b = *(const float4*)(src + 4);
  ushort8 o;
  o[0] = f32_bf16(a.x); o[1] = f32_bf16(a.y); o[2] = f32_bf16(a.z); o[3] = f32_bf16(a.w);
  o[4] = f32_bf16(b.x); o[5] = f32_bf16(b.y); o[6] = f32_bf16(b.z); o[7] = f32_bf16(b.w);
  *(ushort8*)(dst + i * 8) = o;
}

// ----------------------------------------------------------------- rope ----
__global__ __launch_bounds__(256) void rope_table_kernel(float2* __restrict__ tab) {
  int idx = blockIdx.x * 256 + threadIdx.x;
  int t = idx >> 6, i = idx & 63;
  float inv = __expf(-(float)(2 * i) * (1.0f / 128.0f) * 13.122363377404328f);
  float f = (float)t * inv;
  tab[idx] = make_float2(cosf(f), sinf(f));
}

__global__ __launch_bounds__(256) void rope_apply_kernel(
    unsigned short* __restrict__ qkv, const float2* __restrict__ tab) {
  const int row = blockIdx.x;
  const int tid = threadIdx.x;
#pragma unroll
  for (int it = 0; it < 5; ++it) {
    int p = tid + it * 256;
    int head = p >> 6, i = p & 63;
    int col = (p < 1024) ? (head * 128 + 2 * i) : (2048 + (head - 16) * 128 + 2 * i);
    unsigned short* ptr = qkv + (long)row * 3072 + col;
    float a = bf16_f32(ptr[0]), b = bf16_f32(ptr[1]);
    float2 cs = tab[row * 64 + i];
    float a2 = a * cs.x - b * cs.y;
    float b2 = a * cs.y + b * cs.x;
    ptr[0] = f32_bf16(a2);
    ptr[1] = f32_bf16(b2);
  }
}

// -------------------------------------------------------------- rmsnorm ----
__global__ __launch_bounds__(256) void rmsnorm_kernel(
    const float* __restrict__ x, const float* __restrict__ wgt,
    unsigned short* __restrict__ out) {
  __shared__ float red[4];
  const int row = blockIdx.x;
  const int tid = threadIdx.x;
  const float* xr = x + (long)row * 2048 + tid * 8;
  const float4 v0 = *(const float4*)(xr);
  const float4 v1 = *(const float4*)(xr + 4);
  float ss = v0.x * v0.x + v0.y * v0.y + v0.z * v0.z + v0.w * v0.w +
             v1.x * v1.x + v1.y * v1.y + v1.z * v1.z + v1.w * v1.w;
#pragma unroll
  for (int off = 1; off < 64; off <<= 1) ss += __shfl_xor(ss, off);
  if ((tid & 63) == 0) red[tid >> 6] = ss;
  __syncthreads();
  float tot = red[0] + red[1] + red[2] + red[3];
  float sc = rsqrtf(tot * (1.0f / 2048.0f) + 1e-5f);
  const float4 w0 = *(const float4*)(wgt + tid * 8);
  const float4 w1 = *(const float4*)(wgt + tid * 8 + 4);
  ushort8 o;
  o[0] = f32_bf16(v0.x * sc * w0.x); o[1] = f32_bf16(v0.y * sc * w0.y);
  o[2] = f32_bf16(v0.z * sc * w0.z); o[3] = f32_bf16(v0.w * sc * w0.w);
  o[4] = f32_bf16(v1.x * sc * w1.x); o[5] = f32_bf16(v1.y * sc * w1.y);
  o[6] = f32_bf16(v1.z * sc * w1.z); o[7] = f32_bf16(v1.w * sc * w1.w);
  *(ushort8*)(out + (long)row * 2048 + tid * 8) = o;
}

// -------------------------------- deep-flight 4-phase gemm (BM=BN=256) ----
// C[M,N] = A[M,K] @ B[N,K]^T, bf16, f32 acc. BK=64, 8 waves (2Mx4N,
// per-wave 128x64). LDS 128 KiB: [2 buf][2 half] for A and B.
// Schedule (derived from m201 wait algebra; stage lead 1.5 tiles):
//   ph0: read af[m0](8)+bfr[n0](4); stage t+1.B1 -> MFMA m0n0
//   ph1: read bfr[n1](4);           stage t+1.A1 -> MFMA m0n1; vmcnt(6)
//   ph2: read af[m1](8);            stage t+2.A0 -> MFMA m1n0
//   ph3: (no reads)                 stage t+2.B0 -> MFMA m1n1; vmcnt(6)
// Each vmcnt(6) provably drains exactly the halves first-used >=1 phase
// later (outstanding list tracked per phase; tail: vmcnt(0) at t=NT-2.ph3).
// Slot reuse legal: t+2.A0 overwrites a slot last read at ph0 (2+ barriers
// earlier). Granule XOR-swizzle: LDS slot = kseg^(row&7), read offset is a
// per-thread constant; inverse swizzle on GLOBAL source (rule #21).
// EPI 0: bf16. EPI 1: f32 = res+acc. EPI 2: swiglu on interleaved cols.
template <int EPI>
__global__ __launch_bounds__(512, 2) void gemm_dp(
    const unsigned short* __restrict__ A, const unsigned short* __restrict__ B,
    void* __restrict__ Cout, const float* __restrict__ res, int M, int N, int K) {
  __shared__ __align__(16) unsigned short As[2][2][128 * 64];
  __shared__ __align__(16) unsigned short Bs[2][2][128 * 64];

  const int tid = threadIdx.x;
  const int lane = tid & 63;
  const int w = tid >> 6;
  const int c = lane & 15, g = lane >> 4;
  const int a_grp = w >> 2;  // 0..1
  const int b_grp = w & 3;   // 0..3
  const int sw0 = ((g ^ (c & 7)) << 3);
  const int sw1 = (((4 + g) ^ (c & 7)) << 3);

  // bijective XCD swizzle (all grids have nwg % 8 == 0)
  const int id = blockIdx.y * gridDim.x + blockIdx.x;
  const int cpx = (gridDim.x * gridDim.y) >> 3;
  const int sid = (id & 7) * cpx + (id >> 3);
  const int bx = sid % gridDim.x;
  const int by = sid / gridDim.x;
  const long m0 = (long)bx * 256;
  const long n0 = (long)by * 256;

  const f32x4 fzero = {0.f, 0.f, 0.f, 0.f};
  f32x4 acc[2][4][2][2];
#pragma unroll
  for (int qm = 0; qm < 2; ++qm)
#pragma unroll
    for (int mf = 0; mf < 4; ++mf)
#pragma unroll
      for (int qn = 0; qn < 2; ++qn)
#pragma unroll
        for (int nf = 0; nf < 2; ++nf) acc[qm][mf][qn][nf] = fzero;

  auto stageAh = [&](int bufi, int h, int k0) {  // one A half: 2 loads/thread
#pragma unroll
    for (int q = 0; q < 2; ++q) {
      int G = q * 512 + tid;
      int ks = (G & 7) ^ ((G >> 3) & 7);
      async16(&As[bufi][h][(q * 512 + (tid & ~63)) * 8],
              A + (m0 + h * 128 + (G >> 3)) * (long)K + k0 + ks * 8);
    }
  };
  auto stageBh = [&](int bufi, int h, int k0) {
#pragma unroll
    for (int q = 0; q < 2; ++q) {
      int G = q * 512 + tid;
      int ks = (G & 7) ^ ((G >> 3) & 7);
      async16(&Bs[bufi][h][(q * 512 + (tid & ~63)) * 8],
              B + (n0 + h * 128 + (G >> 3)) * (long)K + k0 + ks * 8);
    }
  };

  const int NT = K >> 6;
  // prologue: tile0 fully + tile1 {A0,B0}; issue order matters for vmcnt.
  stageAh(0, 0, 0);
  stageBh(0, 0, 0);
  stageBh(0, 1, 0);
  stageAh(0, 1, 0);
  stageAh(1, 0, 64);
  stageBh(1, 0, 64);
  asm volatile("s_waitcnt vmcnt(6)" ::: "memory");  // t0.A0,B0,B1 resident
  __builtin_amdgcn_s_barrier();

  bf16x8 af[4][2];
  bf16x8 bfr[2][2][2];

  for (int t = 0; t < NT; ++t) {
    const int buf = t & 1;
    const int nbuf = buf ^ 1;
    const int k1 = (t + 1) << 6;
    const int k2 = (t + 2) << 6;
    const bool s1 = (t + 1 < NT), s2 = (t + 2 < NT);

    // ---- ph0: MFMA m0n0 ----
#pragma unroll
    for (int mf = 0; mf < 4; ++mf) {
      const int row = a_grp * 64 + mf * 16 + c;
      af[mf][0] = *(const bf16x8*)(As[buf][0] + row * 64 + sw0);
      af[mf][1] = *(const bf16x8*)(As[buf][0] + row * 64 + sw1);
    }
#pragma unroll
    for (int nf = 0; nf < 2; ++nf) {
      const int row = b_grp * 32 + nf * 16 + c;
      bfr[0][nf][0] = *(const bf16x8*)(Bs[buf][0] + row * 64 + sw0);
      bfr[0][nf][1] = *(const bf16x8*)(Bs[buf][0] + row * 64 + sw1);
    }
    if (s1) stageBh(nbuf, 1, k1);
    __builtin_amdgcn_s_barrier();
    asm volatile("s_waitcnt lgkmcnt(0)" ::: "memory");
    __builtin_amdgcn_sched_barrier(0);
    __builtin_amdgcn_s_setprio(1);
#pragma unroll
    for (int kk = 0; kk < 2; ++kk)
#pragma unroll
      for (int mf = 0; mf < 4; ++mf)
#pragma unroll
        for (int nf = 0; nf < 2; ++nf)
          acc[0][mf][0][nf] = __builtin_amdgcn_mfma_f32_16x16x32_bf16(
              af[mf][kk], bfr[0][nf][kk], acc[0][mf][0][nf], 0, 0, 0);
    __builtin_amdgcn_s_setprio(0);
    __builtin_amdgcn_s_barrier();

    // ---- ph1: MFMA m0n1 ----
#pragma unroll
    for (int nf = 0; nf < 2; ++nf) {
      const int row = b_grp * 32 + nf * 16 + c;
      bfr[1][nf][0] = *(const bf16x8*)(Bs[buf][1] + row * 64 + sw0);
      bfr[1][nf][1] = *(const bf16x8*)(Bs[buf][1] + row * 64 + sw1);
    }
    if (s1) stageAh(nbuf, 1, k1);
    __builtin_amdgcn_s_barrier();
    asm volatile("s_waitcnt lgkmcnt(0)" ::: "memory");
    __builtin_amdgcn_sched_barrier(0);
    __builtin_amdgcn_s_setprio(1);
#pragma unroll
    for (int kk = 0; kk < 2; ++kk)
#pragma unroll
      for (int mf = 0; mf < 4; ++mf)
#pragma unroll
        for (int nf = 0; nf < 2; ++nf)
          acc[0][mf][1][nf] = __builtin_amdgcn_mfma_f32_16x16x32_bf16(
              af[mf][kk], bfr[1][nf][kk], acc[0][mf][1][nf], 0, 0, 0);
    __builtin_amdgcn_s_setprio(0);
    if (s1) asm volatile("s_waitcnt vmcnt(6)" ::: "memory");
    __builtin_amdgcn_s_barrier();

    // ---- ph2: MFMA m1n0 ----
#pragma unroll
    for (int mf = 0; mf < 4; ++mf) {
      const int row = a_grp * 64 + mf * 16 + c;
      af[mf][0] = *(const bf16x8*)(As[buf][1] + row * 64 + sw0);
      af[mf][1] = *(const bf16x8*)(As[buf][1] + row * 64 + sw1);
    }
    if (s2) stageAh(buf, 0, k2);
    __builtin_amdgcn_s_barrier();
    asm volatile("s_waitcnt lgkmcnt(0)" ::: "memory");
    __builtin_amdgcn_sched_barrier(0);
    __builtin_amdgcn_s_setprio(1);
#pragma unroll
    for (int kk = 0; kk < 2; ++kk)
#pragma unroll
      for (int mf = 0; mf < 4; ++mf)
#pragma unroll
        for (int nf = 0; nf < 2; ++nf)
          acc[1][mf][0][nf] = __builtin_amdgcn_mfma_f32_16x16x32_bf16(
              af[mf][kk], bfr[0][nf][kk], acc[1][mf][0][nf], 0, 0, 0);
    __builtin_amdgcn_s_setprio(0);
    __builtin_amdgcn_s_barrier();

    // ---- ph3: MFMA m1n1 (no ds_reads; operands in regs) ----
    if (s2) stageBh(buf, 0, k2);
    __builtin_amdgcn_s_setprio(1);
#pragma unroll
    for (int kk = 0; kk < 2; ++kk)
#pragma unroll
      for (int mf = 0; mf < 4; ++mf)
#pragma unroll
        for (int nf = 0; nf < 2; ++nf)
          acc[1][mf][1][nf] = __builtin_amdgcn_mfma_f32_16x16x32_bf16(
              af[mf][kk], bfr[1][nf][kk], acc[1][mf][1][nf], 0, 0, 0);
    __builtin_amdgcn_s_setprio(0);
    if (s2)
      asm volatile("s_waitcnt vmcnt(6)" ::: "memory");
    else if (s1)
      asm volatile("s_waitcnt vmcnt(0)" ::: "memory");
    __builtin_amdgcn_s_barrier();
  }

  // ---- epilogue ----
#pragma unroll
  for (int qm = 0; qm < 2; ++qm) {
#pragma unroll
    for (int mf = 0; mf < 4; ++mf) {
#pragma unroll
      for (int qn = 0; qn < 2; ++qn) {
#pragma unroll
        for (int nf = 0; nf < 2; ++nf) {
          const long row0 = m0 + qm * 128 + a_grp * 64 + mf * 16 + g * 4;
          const long col = n0 + qn * 128 + b_grp * 32 + nf * 16 + c;
#pragma unroll
          for (int r = 0; r < 4; ++r) {
            float v = acc[qm][mf][qn][nf][r];
            if (EPI == 0) {
              ((unsigned short*)Cout)[(row0 + r) * N + col] = f32_bf16(v);
            } else if (EPI == 1) {
              ((float*)Cout)[(row0 + r) * N + col] = res[(row0 + r) * N + col] + v;
            } else {
              float other = __shfl_xor(v, 1);
              if (!(c & 1)) {
                float sg = v / (1.0f + __expf(-v));
                ((unsigned short*)Cout)[(row0 + r) * (long)(N >> 1) + (col >> 1)] =
                    f32_bf16(sg * other);
              }
            }
          }
        }
      }
    }
  }
}

// ------------------------------------- BK=32 4-buffer gemm (proven, BN=128) ----
// Round-6 structure (best measured for N=2048 shapes); see prior notes.
template <int BN, int EPI>
__global__ __launch_bounds__(512, 2) void gemm_p(
    const unsigned short* __restrict__ A, const unsigned short* __restrict__ B,
    void* __restrict__ Cout, const float* __restrict__ res, int M, int N, int K) {
  constexpr int MH = (BN == 256) ? 2 : 1;
  constexpr int MF = MH * 4;
  constexpr int BL = (BN == 256) ? 2 : 1;
  __shared__ __align__(16) unsigned short As[4][256 * 32];
  __shared__ __align__(16) unsigned short Bs[4][BN * 32];

  const int tid = threadIdx.x;
  const int lane = tid & 63;
  const int w = tid >> 6;
  const int c = lane & 15, g = lane >> 4;
  const int wm = (BN == 256) ? (w >> 2) * 128 : (w >> 1) * 64;
  const int wn = (BN == 256) ? (w & 3) * 64 : (w & 1) * 64;
  const int gs = ((g ^ ((c >> 1) & 3)) << 3);

  const int id = blockIdx.y * gridDim.x + blockIdx.x;
  const int cpx = (gridDim.x * gridDim.y) >> 3;
  const int sid = (id & 7) * cpx + (id >> 3);
  const int bx = sid % gridDim.x;
  const int by = sid / gridDim.x;
  const long m0 = (long)bx * 256;
  const long n0 = (long)by * BN;

  const f32x4 fzero = {0.f, 0.f, 0.f, 0.f};
  f32x4 acc[MF][4];
#pragma unroll
  for (int i = 0; i < MF; ++i)
#pragma unroll
    for (int j = 0; j < 4; ++j) acc[i][j] = fzero;

  auto stageA = [&](int buf, int k0) {
#pragma unroll
    for (int q = 0; q < 2; ++q) {
      int G = q * 512 + tid;
      int sg = (G & 3) ^ ((G >> 3) & 3);
      async16(&As[buf][(q * 512 + (tid & ~63)) * 8],
              A + (m0 + (G >> 2)) * (long)K + k0 + sg * 8);
    }
  };
  auto stageB = [&](int buf, int k0) {
#pragma unroll
    for (int q = 0; q < BL; ++q) {
      int G = q * 512 + tid;
      int sg = (G & 3) ^ ((G >> 3) & 3);
      async16(&Bs[buf][(q * 512 + (tid & ~63)) * 8],
              B + (n0 + (G >> 2)) * (long)K + k0 + sg * 8);
    }
  };

  const int NT = K >> 5;
  stageA(0, 0);
  stageB(0, 0);
  stageA(1, 32);
  stageB(1, 32);
  if constexpr (BN == 256)
    asm volatile("s_waitcnt vmcnt(4)" ::: "memory");
  else
    asm volatile("s_waitcnt vmcnt(3)" ::: "memory");
  __builtin_amdgcn_s_barrier();

  for (int t = 0; t < NT; ++t) {
    const int buf = t & 3;
    const unsigned short* Ab = As[buf];
    const unsigned short* Bb = Bs[buf];
    const bool pf = (t + 2 < NT);
    const int nb = (t + 2) & 3;

    bf16x8 bfr[4];
#pragma unroll
    for (int nf = 0; nf < 4; ++nf)
      bfr[nf] = *(const bf16x8*)(Bb + (wn + nf * 16 + c) * 32 + gs);

#pragma unroll
    for (int mh = 0; mh < MH; ++mh) {
      bf16x8 af[4];
#pragma unroll
      for (int mf = 0; mf < 4; ++mf)
        af[mf] = *(const bf16x8*)(Ab + (wm + mh * 64 + mf * 16 + c) * 32 + gs);
      if (pf) {
        if (mh == 0) stageA(nb, (t + 2) << 5);
        if (mh == MH - 1) stageB(nb, (t + 2) << 5);
      }
      __builtin_amdgcn_sched_barrier(0);
      __builtin_amdgcn_s_setprio(1);
#pragma unroll
      for (int mf = 0; mf < 4; ++mf)
#pragma unroll
        for (int nf = 0; nf < 4; ++nf)
          acc[mh * 4 + mf][nf] = __builtin_amdgcn_mfma_f32_16x16x32_bf16(
              af[mf], bfr[nf], acc[mh * 4 + mf][nf], 0, 0, 0);
      __builtin_amdgcn_s_setprio(0);
    }

    if (pf) {
      if constexpr (BN == 256)
        asm volatile("s_waitcnt vmcnt(4)" ::: "memory");
      else
        asm volatile("s_waitcnt vmcnt(3)" ::: "memory");
    } else {
      asm volatile("s_waitcnt vmcnt(0)" ::: "memory");
    }
    __builtin_amdgcn_s_barrier();
  }

#pragma unroll
  for (int i = 0; i < MF; ++i) {
#pragma unroll
    for (int j = 0; j < 4; ++j) {
      const long row0 = m0 + wm + i * 16 + g * 4;
      const long col = n0 + wn + j * 16 + c;
#pragma unroll
      for (int r = 0; r < 4; ++r) {
        float v = acc[i][j][r];
        if (EPI == 0) {
          ((unsigned short*)Cout)[(row0 + r) * N + col] = f32_bf16(v);
        } else if (EPI == 1) {
          ((float*)Cout)[(row0 + r) * N + col] = res[(row0 + r) * N + col] + v;
        } else {
          float other = __shfl_xor(v, 1);
          if (!(c & 1)) {
            float sg2 = v / (1.0f + __expf(-v));
            ((unsigned short*)Cout)[(row0 + r) * (long)(N >> 1) + (col >> 1)] =
                f32_bf16(sg2 * other);
          }
        }
      }
    }
  }
}

// ----------------------------------------------------------- v transpose ----
__global__ __launch_bounds__(256) void transpose_v(
    const unsigned short* __restrict__ qkv, unsigned short* __restrict__ vT) {
  __shared__ __align__(16) unsigned short tile[64][72];
  const int tx = blockIdx.x;
  const int dx = blockIdx.y;
  const int tid = threadIdx.x;
  const int r = tid >> 3, cg = tid & 7;
#pragma unroll
  for (int it = 0; it < 2; ++it) {
    const unsigned short* src =
        qkv + (long)(tx * 64 + r + it * 32) * 3072 + 2560 + dx * 64 + cg * 8;
    *(ushort8*)(&tile[r + it * 32][cg * 8]) = *(const ushort8*)src;
  }
  __syncthreads();
#pragma unroll
  for (int it = 0; it < 2; ++it) {
    int d = r + it * 32;
    ushort8 v;
#pragma unroll
    for (int j = 0; j < 8; ++j) v[j] = tile[cg * 8 + j][d];
    *(ushort8*)(vT + (long)(dx * 64 + d) * 4096 + tx * 64 + cg * 8) = v;
  }
}

// ------------------------------------------------------------- attention ----
// Swapped-operand causal GQA flash attention (see round-1 notes).
__global__ __launch_bounds__(512, 2) void attn_kernel(
    const unsigned short* __restrict__ qkv, const unsigned short* __restrict__ vT,
    unsigned short* __restrict__ y) {
  constexpr float SCL = 0.08838834764831845f * 1.4426950408889634f;
  __shared__ __align__(16) unsigned short Kb[2][64 * 128];
  __shared__ __align__(16) unsigned short Vb[2][128 * 64];

  const int tid = threadIdx.x;
  const int lane = tid & 63;
  const int w = tid >> 6;
  const int c = lane & 15, g = lane >> 4;
  const int h = blockIdx.x >> 4;
  const int pid = blockIdx.x & 15;
  const int kvh = h >> 2;
  const int qt = (w < 4) ? pid : (31 - pid);
  const int q0w = qt * 128 + (w & 3) * 32;
  const int nsteps = 2 * (31 - pid) + 2;

  const f32x4 fzero = {0.f, 0.f, 0.f, 0.f};

  bf16x8 qf[2][4];
#pragma unroll
  for (int mt = 0; mt < 2; ++mt)
#pragma unroll
    for (int kk = 0; kk < 4; ++kk)
      qf[mt][kk] = *(const bf16x8*)(qkv + (long)(q0w + mt * 16 + c) * 3072 +
                                    h * 128 + kk * 32 + g * 8);

  f32x4 o[2][8];
#pragma unroll
  for (int mt = 0; mt < 2; ++mt)
#pragma unroll
    for (int dt = 0; dt < 8; ++dt) o[mt][dt] = fzero;
  float m[2] = {-1e30f, -1e30f}, l[2] = {0.f, 0.f};

  auto stage = [&](int buf, int kv0) {
#pragma unroll
    for (int k = 0; k < 2; ++k) {
      int G = k * 512 + tid;
      int row = G >> 4, colg = (G & 15) ^ (row & 7);
      async16(&Kb[buf][(k * 512 + (tid & ~63)) * 8],
              qkv + (long)(kv0 + row) * 3072 + 2048 + kvh * 128 + colg * 8);
    }
#pragma unroll
    for (int k = 0; k < 2; ++k) {
      int G = k * 512 + tid;
      int row = G >> 3, colg = (G & 7) ^ (row & 7);
      async16(&Vb[buf][(k * 512 + (tid & ~63)) * 8],
              vT + (long)(kvh * 128 + row) * 4096 + kv0 + colg * 8);
    }
  };

  stage(0, 0);
  for (int s = 0; s < nsteps; ++s) {
    const int kv0 = s * 64;
    const int bi = s & 1;
    if (s + 1 < nsteps) {
      stage(bi ^ 1, kv0 + 64);
      asm volatile("s_waitcnt vmcnt(4)" ::: "memory");
    } else {
      asm volatile("s_waitcnt vmcnt(0)" ::: "memory");
    }
    __builtin_amdgcn_s_barrier();
    if (kv0 <= q0w + 31) {
      const unsigned short* Ks = Kb[bi];
      const unsigned short* Vs = Vb[bi];
      f32x4 sv[2][4];
#pragma unroll
      for (int mt = 0; mt < 2; ++mt)
#pragma unroll
        for (int nt = 0; nt < 4; ++nt) sv[mt][nt] = fzero;
#pragma unroll
      for (int kk = 0; kk < 4; ++kk) {
        bf16x8 kf[4];
#pragma unroll
        for (int nt = 0; nt < 4; ++nt)
          kf[nt] = *(const bf16x8*)(Ks + (nt * 16 + c) * 128 +
                                    (((kk * 4 + g) ^ (c & 7)) << 3));
#pragma unroll
        for (int mt = 0; mt < 2; ++mt)
#pragma unroll
          for (int nt = 0; nt < 4; ++nt)
            sv[mt][nt] = __builtin_amdgcn_mfma_f32_16x16x32_bf16(
                kf[nt], qf[mt][kk], sv[mt][nt], 0, 0, 0);
      }
      const bool need_mask = (kv0 + 63 > q0w);
      float al[2];
#pragma unroll
      for (int mt = 0; mt < 2; ++mt) {
        const int qrow = q0w + mt * 16 + c;
#pragma unroll
        for (int nt = 0; nt < 4; ++nt)
#pragma unroll
          for (int r = 0; r < 4; ++r) {
            float xx = sv[mt][nt][r] * SCL;
            if (need_mask && (kv0 + nt * 16 + g * 4 + r > qrow)) xx = -3.0e38f;
            sv[mt][nt][r] = xx;
          }
        float mx = -3.0e38f;
#pragma unroll
        for (int nt = 0; nt < 4; ++nt)
#pragma unroll
          for (int r = 0; r < 4; ++r) mx = fmaxf(mx, sv[mt][nt][r]);
        mx = fmaxf(mx, __shfl_xor(mx, 16));
        mx = fmaxf(mx, __shfl_xor(mx, 32));
        const float mn = fmaxf(m[mt], mx);
        const float a = exp2f(m[mt] - mn);
        m[mt] = mn;
        al[mt] = a;
        float rs = 0.f;
#pragma unroll
        for (int nt = 0; nt < 4; ++nt)
#pragma unroll
          for (int r = 0; r < 4; ++r) {
            float p = exp2f(sv[mt][nt][r] - mn);
            sv[mt][nt][r] = p;
            rs += p;
          }
        rs += __shfl_xor(rs, 16);
        rs += __shfl_xor(rs, 32);
        l[mt] = l[mt] * a + rs;
#pragma unroll
        for (int dt = 0; dt < 8; ++dt) o[mt][dt] *= al[mt];
      }
#pragma unroll
      for (int nt = 0; nt < 4; ++nt) {
        bf16x4 pb[2];
#pragma unroll
        for (int mt = 0; mt < 2; ++mt) {
          int lo_, hi_;
          float s0 = sv[mt][nt][0], s1 = sv[mt][nt][1];
          float s2 = sv[mt][nt][2], s3 = sv[mt][nt][3];
          asm("v_cvt_pk_bf16_f32 %0, %1, %2" : "=v"(lo_) : "v"(s0), "v"(s1));
          asm("v_cvt_pk_bf16_f32 %0, %1, %2" : "=v"(hi_) : "v"(s2), "v"(s3));
          int2 pk = make_int2(lo_, hi_);
          pb[mt] = __builtin_bit_cast(bf16x4, pk);
        }
#pragma unroll
        for (int dt = 0; dt < 8; ++dt) {
          bf16x4 vt = *(const bf16x4*)(Vs + (dt * 16 + c) * 64 +
                                       (((nt * 2 + (g >> 1)) ^ (c & 7)) << 3) +
                                       (g & 1) * 4);
          o[0][dt] = mfma16(vt, pb[0], o[0][dt]);
          o[1][dt] = mfma16(vt, pb[1], o[1][dt]);
        }
      }
    }
    __builtin_amdgcn_s_barrier();
  }
#pragma unroll
  for (int mt = 0; mt < 2; ++mt) {
    const float inv = 1.0f / l[mt];
    const long qrow = q0w + mt * 16 + c;
#pragma unroll
    for (int dt = 0; dt < 8; ++dt) {
      us4 st;
      st[0] = f32_bf16(o[mt][dt][0] * inv);
      st[1] = f32_bf16(o[mt][dt][1] * inv);
      st[2] = f32_bf16(o[mt][dt][2] * inv);
      st[3] = f32_bf16(o[mt][dt][3] * inv);
      *(us4*)(y + qrow * 2048 + h * 128 + dt * 16 + g * 4) = st;
    }
  }
}

// ------------------------------------------------------------------ host ----
extern "C" void kernel_launch(void* const* d_in, const int* in_sizes, int n_in,
                              void* d_out, int out_size, void* d_ws, size_t ws_size,
                              hipStream_t stream) {
  (void)in_sizes; (void)n_in; (void)out_size; (void)ws_size;
  const float* x      = (const float*)d_in[0];
  const float* attn_w = (const float*)d_in[2];
  const float* wq     = (const float*)d_in[3];
  const float* wk     = (const float*)d_in[4];
  const float* wv     = (const float*)d_in[5];
  const float* wo     = (const float*)d_in[6];
  const float* ffn_w  = (const float*)d_in[7];
  const float* wg     = (const float*)d_in[8];
  const float* wu     = (const float*)d_in[9];
  const float* wd     = (const float*)d_in[10];
  float* out = (float*)d_out;

  char* ws = (char*)d_ws;
  size_t off = 0;
  auto alloc = [&](size_t bytes) {
    char* p = ws + off;
    off += (bytes + 255) & ~(size_t)255;
    return p;
  };
  float2* rope_tab        = (float2*)alloc(4096UL * 64 * sizeof(float2));
  unsigned short* wqkv_b  = (unsigned short*)alloc(3072UL * 2048 * 2);
  unsigned short* wo_b    = (unsigned short*)alloc(2048UL * 2048 * 2);
  unsigned short* wgu_b   = (unsigned short*)alloc(16384UL * 2048 * 2);
  unsigned short* wd_b    = (unsigned short*)alloc(2048UL * 8192 * 2);
  unsigned short* h_b     = (unsigned short*)alloc(4096UL * 2048 * 2);
  unsigned short* qkv_b   = (unsigned short*)alloc(4096UL * 3072 * 2);
  unsigned short* vT_b    = (unsigned short*)alloc(512UL * 4096 * 2);
  unsigned short* y_b     = (unsigned short*)alloc(4096UL * 2048 * 2);
  float* r1               = (float*)alloc(4096UL * 2048 * 4);
  unsigned short* t_b     = (unsigned short*)alloc(4096UL * 8192 * 2);

  // weight casts
  cast_bf16_kernel<<<2048, 256, 0, stream>>>(wq, wqkv_b, 524288);
  cast_bf16_kernel<<<512, 256, 0, stream>>>(wk, wqkv_b + 2048L * 2048, 131072);
  cast_bf16_kernel<<<512, 256, 0, stream>>>(wv, wqkv_b + 2560L * 2048, 131072);
  cast_bf16_kernel<<<2048, 256, 0, stream>>>(wo, wo_b, 524288);
  cast_gu_kernel<<<16384, 256, 0, stream>>>(wg, wu, wgu_b);
  cast_bf16_kernel<<<8192, 256, 0, stream>>>(wd, wd_b, 2097152);
  rope_table_kernel<<<1024, 256, 0, stream>>>(rope_tab);

  // attn branch
  rmsnorm_kernel<<<4096, 256, 0, stream>>>(x, attn_w, h_b);
  {
    dim3 grid(16, 12);
    gemm_dp<0><<<grid, 512, 0, stream>>>(h_b, wqkv_b, qkv_b, nullptr, 4096, 3072, 2048);
  }
  rope_apply_kernel<<<4096, 256, 0, stream>>>(qkv_b, rope_tab);
  {
    dim3 grid(64, 8);
    transpose_v<<<grid, 256, 0, stream>>>(qkv_b, vT_b);
  }
  attn_kernel<<<256, 512, 0, stream>>>(qkv_b, vT_b, y_b);
  {
    dim3 grid(16, 16);
    gemm_p<128, 1><<<grid, 512, 0, stream>>>(y_b, wo_b, r1, x, 4096, 2048, 2048);
  }

  // ffn branch
  rmsnorm_kernel<<<4096, 256, 0, stream>>>(r1, ffn_w, h_b);
  {
    dim3 grid(16, 64);
    gemm_dp<2><<<grid, 512, 0, stream>>>(h_b, wgu_b, t_b, nullptr, 4096, 16384, 2048);
  }
  {
    dim3 grid(16, 16);
    gemm_p<128, 1><<<grid, 512, 0, stream>>>(t_b, wd_b, out, r1, 4096, 2048, 8192);
  }
}